// Round 5
// baseline (10183.582 us; speedup 1.0000x reference)
//
#include <hip/hip_runtime.h>

namespace {

constexpr int B = 32, H = 512, L = 2, T = 20, V = 10000, S = 49;
constexpr unsigned NBLK = 512;

__device__ __forceinline__ float sigf(float x) { return 1.0f / (1.0f + expf(-x)); }
__device__ __forceinline__ float dot4(float4 a, float4 b) {
  return a.x*b.x + a.y*b.y + a.z*b.z + a.w*b.w;
}

// ---- software grid barrier (device-scope atomics; monotonic counter) ----
__device__ __forceinline__ void grid_bar(unsigned* cnt, unsigned& target, int tid) {
  __syncthreads();
  target += NBLK;
  if (tid == 0) {
    __hip_atomic_fetch_add(cnt, 1u, __ATOMIC_ACQ_REL, __HIP_MEMORY_SCOPE_AGENT);
    while (__hip_atomic_load(cnt, __ATOMIC_ACQUIRE, __HIP_MEMORY_SCOPE_AGENT) < target) {
      __builtin_amdgcn_s_sleep(1);
    }
  }
  __syncthreads();
}

// ---- LSTM layer: block = one hi; all 4 gates x 32 batches ----
__device__ void dev_lstm_layer(const float* __restrict__ x,
                               const float* __restrict__ hprev,
                               float* __restrict__ cio,
                               const float* __restrict__ WihL,
                               const float* __restrict__ WhhL,
                               const float* __restrict__ bihL,
                               const float* __restrict__ bhhL,
                               float* __restrict__ hout,
                               int hi, float* smem, int tid) {
  int ko = tid & 15, rr = (tid >> 4) & 3, bh = tid >> 6;
  const float* wih = WihL + ((size_t)rr * H + hi) * H;
  const float* whh = WhhL + ((size_t)rr * H + hi) * H;
  float4 wi[8], wh[8];
#pragma unroll
  for (int kk = 0; kk < 8; ++kk) {
    wi[kk] = *(const float4*)&wih[kk * 64 + ko * 4];
    wh[kk] = *(const float4*)&whh[kk * 64 + ko * 4];
  }
  float bias = bihL[rr * H + hi] + bhhL[rr * H + hi];
  float* gbuf = smem + 8448;   // 128 floats
  for (int g = 0; g < 4; ++g) {   // 8 batches per group
    __syncthreads();
    const float4* xg = (const float4*)(x + (size_t)g * 8 * H);
    const float4* hg = (const float4*)(hprev + (size_t)g * 8 * H);
    float4* s4 = (float4*)smem;
    for (int i = tid; i < 1024; i += 256) s4[i] = xg[i];
    for (int i = tid; i < 1024; i += 256) s4[1024 + i] = hg[i];
    __syncthreads();
    const float* xb0 = smem + (bh * 2 + 0) * 512;
    const float* xb1 = smem + (bh * 2 + 1) * 512;
    const float* hb0 = smem + 4096 + (bh * 2 + 0) * 512;
    const float* hb1 = smem + 4096 + (bh * 2 + 1) * 512;
    float a0 = 0.f, a1 = 0.f;
#pragma unroll
    for (int kk = 0; kk < 8; ++kk) {
      a0 += dot4(*(const float4*)&xb0[kk * 64 + ko * 4], wi[kk]);
      a0 += dot4(*(const float4*)&hb0[kk * 64 + ko * 4], wh[kk]);
      a1 += dot4(*(const float4*)&xb1[kk * 64 + ko * 4], wi[kk]);
      a1 += dot4(*(const float4*)&hb1[kk * 64 + ko * 4], wh[kk]);
    }
    a0 += __shfl_xor(a0, 1); a0 += __shfl_xor(a0, 2);
    a0 += __shfl_xor(a0, 4); a0 += __shfl_xor(a0, 8);
    a1 += __shfl_xor(a1, 1); a1 += __shfl_xor(a1, 2);
    a1 += __shfl_xor(a1, 4); a1 += __shfl_xor(a1, 8);
    if (ko == 0) {
      gbuf[rr * 32 + g * 8 + bh * 2 + 0] = a0 + bias;
      gbuf[rr * 32 + g * 8 + bh * 2 + 1] = a1 + bias;
    }
  }
  __syncthreads();
  if (tid < 32) {
    int b = tid;
    float gi = gbuf[b], gf = gbuf[32 + b], gg = gbuf[64 + b], go = gbuf[96 + b];
    float c2 = sigf(gf) * cio[b * H + hi] + sigf(gi) * tanhf(gg);
    hout[b * H + hi] = sigf(go) * tanhf(c2);
    cio[b * H + hi] = c2;
  }
}

// ---- vocab projection tile: 16 v-rows x all 32 batches (two halves) ----
__device__ void dev_proj_tile(const float* __restrict__ xin,
                              const float* __restrict__ projW,
                              const float* __restrict__ projb,
                              float* __restrict__ logits,
                              float* __restrict__ ocol, int direct, int tcol,
                              int v0, float* smem, int tid) {
  int ko = tid & 15, vl = tid >> 4;
  int v = v0 + vl;
  const float* wrow = projW + (size_t)v * H;
  float4 w[8];
#pragma unroll
  for (int kk = 0; kk < 8; ++kk) w[kk] = *(const float4*)&wrow[kk * 64 + ko * 4];
  float bias = projb[v];
  for (int half = 0; half < 2; ++half) {
    __syncthreads();
    const float4* xg = (const float4*)(xin + (size_t)half * 16 * H);
    float4* s4 = (float4*)smem;
    for (int i = tid; i < 2048; i += 256) s4[i] = xg[i];
    __syncthreads();
    float acc[16];
#pragma unroll
    for (int b = 0; b < 16; ++b) acc[b] = 0.f;
    for (int b = 0; b < 16; ++b) {
      const float* xb = smem + b * 512;
#pragma unroll
      for (int kk = 0; kk < 8; ++kk)
        acc[b] += dot4(*(const float4*)&xb[kk * 64 + ko * 4], w[kk]);
    }
#pragma unroll
    for (int b = 0; b < 16; ++b) {
      acc[b] += __shfl_xor(acc[b], 1);
      acc[b] += __shfl_xor(acc[b], 2);
      acc[b] += __shfl_xor(acc[b], 4);
      acc[b] += __shfl_xor(acc[b], 8);
    }
    if (ko == 0) {
      for (int b = 0; b < 16; ++b) {
        int bb = half * 16 + b;
        float r = acc[b] + bias;
        logits[bb * V + v] = r;
        if (direct) ocol[((size_t)bb * V + v) * T + tcol] = r;
        else        ocol[bb * V + v] = r;
      }
    }
  }
}

// ---- q GEMV tile: 16 j x 32 lb of one layer (two halves) ----
__device__ void dev_q_tile(const float* __restrict__ hmid_all,
                           const float* __restrict__ Wq,
                           const float* __restrict__ bq,
                           float* __restrict__ q, int tile,
                           float* smem, int tid) {
  int lg = tile & 1, jg = tile >> 1;
  int ko = tid & 15, jl = tid >> 4;
  int j = jg * 16 + jl;
  const float* wrow = Wq + (size_t)j * H;
  float4 w[8];
#pragma unroll
  for (int kk = 0; kk < 8; ++kk) w[kk] = *(const float4*)&wrow[kk * 64 + ko * 4];
  float bias = bq[j];
  for (int half = 0; half < 2; ++half) {
    __syncthreads();
    const float4* xg = (const float4*)(hmid_all + ((size_t)lg * 32 + half * 16) * H);
    float4* s4 = (float4*)smem;
    for (int i = tid; i < 2048; i += 256) s4[i] = xg[i];
    __syncthreads();
    float acc[16];
#pragma unroll
    for (int b = 0; b < 16; ++b) acc[b] = 0.f;
    for (int b = 0; b < 16; ++b) {
      const float* xb = smem + b * 512;
#pragma unroll
      for (int kk = 0; kk < 8; ++kk)
        acc[b] += dot4(*(const float4*)&xb[kk * 64 + ko * 4], w[kk]);
    }
#pragma unroll
    for (int b = 0; b < 16; ++b) {
      acc[b] += __shfl_xor(acc[b], 1);
      acc[b] += __shfl_xor(acc[b], 2);
      acc[b] += __shfl_xor(acc[b], 4);
      acc[b] += __shfl_xor(acc[b], 8);
    }
    if (ko == 0) {
      for (int b = 0; b < 16; ++b)
        q[((size_t)lg * 32 + half * 16 + b) * H + j] = tanhf(acc[b] + bias);
    }
  }
}

// ---- scores -> softmax -> attn -> cat (per lb) ----
__device__ void dev_sattn(const float* __restrict__ q,
                          const float* __restrict__ keysT,
                          const float* __restrict__ valuesT,
                          const float* __restrict__ hmid,
                          float* __restrict__ cat,
                          int lb, float* smem, int tid) {
  float* qv = smem;          // 528
  float* scl = smem + 528;   // 64
  float* wts = smem + 592;   // 64
  int b = lb & 31;
  {
    int c0 = tid, c1 = tid + 256;
    qv[(c0 >> 7) * 132 + (c0 & 127)] = q[lb * H + c0];
    qv[(c1 >> 7) * 132 + (c1 & 127)] = q[lb * H + c1];
  }
  __syncthreads();
  int kq = tid & 3, sl = tid >> 2;
  float acc = 0.f;
  if (sl < S) {
    const float* kr = keysT + ((size_t)b * S + sl) * H + kq * 128;
    const float* qr = &qv[kq * 132];
    for (int k = 0; k < 128; k += 4)
      acc += dot4(*(const float4*)&qr[k], *(const float4*)&kr[k]);
  }
  acc += __shfl_xor(acc, 1);
  acc += __shfl_xor(acc, 2);
  if (kq == 0 && sl < S) scl[sl] = acc * (1.0f / 7.0f);
  __syncthreads();
  if (tid < 64) {
    float sc = (tid < S) ? scl[tid] : -3.4e38f;
    float m = sc;
    for (int o = 32; o > 0; o >>= 1) m = fmaxf(m, __shfl_xor(m, o));
    float e = (tid < S) ? expf(sc - m) : 0.f;
    float sum = e;
    for (int o = 32; o > 0; o >>= 1) sum += __shfl_xor(sum, o);
    if (tid < S) wts[tid] = e / sum;
  }
  __syncthreads();
  float acc0 = 0.f, acc1 = 0.f;
  for (int s = 0; s < S; ++s) {
    float w = wts[s];
    const float* vr = valuesT + ((size_t)b * S + s) * H;
    acc0 += w * vr[tid];
    acc1 += w * vr[tid + 256];
  }
  cat[lb * 1024 + tid] = acc0;
  cat[lb * 1024 + tid + 256] = acc1;
  cat[lb * 1024 + 512 + tid] = hmid[lb * H + tid];
  cat[lb * 1024 + 768 + tid] = hmid[lb * H + tid + 256];
}

// ---- greedy argmax + embedding gather (per b) ----
__device__ void dev_argmax_embed(const float* __restrict__ logits,
                                 const float* __restrict__ embed,
                                 float* __restrict__ emb,
                                 int b, float* smem, int tid) {
  float* sv = smem;
  int* si = (int*)(smem + 256);
  float best = -3.4e38f;
  int bi = 0x7fffffff;
  for (int it = 0; it < 10; ++it) {
    int v0 = it * 1024 + tid * 4;
    if (v0 < V) {
      float4 lv = *(const float4*)&logits[b * V + v0];
      if (lv.x > best) { best = lv.x; bi = v0; }
      if (lv.y > best) { best = lv.y; bi = v0 + 1; }
      if (lv.z > best) { best = lv.z; bi = v0 + 2; }
      if (lv.w > best) { best = lv.w; bi = v0 + 3; }
    }
  }
  sv[tid] = best; si[tid] = bi;
  __syncthreads();
  for (int st = 128; st > 0; st >>= 1) {
    if (tid < st) {
      float ov = sv[tid + st]; int oi = si[tid + st];
      if (ov > sv[tid] || (ov == sv[tid] && oi < si[tid])) { sv[tid] = ov; si[tid] = oi; }
    }
    __syncthreads();
  }
  int idx = si[0];
  for (int i = tid; i < H; i += 256) emb[b * H + i] = embed[(size_t)idx * H + i];
}

// ---- gated hidden update tile: 16 j x 16 lb (two halves of 8) ----
__device__ void dev_hatt(const float* __restrict__ cat,
                         const float* __restrict__ hattW,
                         const float* __restrict__ hattb,
                         float* __restrict__ h,
                         int blk, float* smem, int tid) {
  int lbg = blk & 3, jg = blk >> 2;
  int ko = tid & 15, jl = tid >> 4;
  int j = jg * 16 + jl;
  const float* wrow = hattW + (size_t)j * 1024;
  float4 w[16];
#pragma unroll
  for (int kk = 0; kk < 16; ++kk) w[kk] = *(const float4*)&wrow[kk * 64 + ko * 4];
  float bias = hattb[j];
  for (int half = 0; half < 2; ++half) {
    __syncthreads();
    const float4* cg4 = (const float4*)(cat + ((size_t)lbg * 16 + half * 8) * 1024);
    float4* s4 = (float4*)smem;
    for (int i = tid; i < 2048; i += 256) s4[i] = cg4[i];
    __syncthreads();
    float acc[8];
#pragma unroll
    for (int lb = 0; lb < 8; ++lb) acc[lb] = 0.f;
    for (int lb = 0; lb < 8; ++lb) {
      const float* cb = smem + lb * 1024;
#pragma unroll
      for (int kk = 0; kk < 16; ++kk)
        acc[lb] += dot4(*(const float4*)&cb[kk * 64 + ko * 4], w[kk]);
    }
#pragma unroll
    for (int lb = 0; lb < 8; ++lb) {
      acc[lb] += __shfl_xor(acc[lb], 1);
      acc[lb] += __shfl_xor(acc[lb], 2);
      acc[lb] += __shfl_xor(acc[lb], 4);
      acc[lb] += __shfl_xor(acc[lb], 8);
    }
    if (ko == 0) {
      for (int lb = 0; lb < 8; ++lb)
        h[((size_t)lbg * 16 + half * 8 + lb) * H + j] = tanhf(acc[lb] + bias);
    }
  }
}

__global__ void bar_init_kernel(unsigned* cnt) {
  if (threadIdx.x == 0) cnt[0] = 0;
}

__global__ __launch_bounds__(256, 2) void persist_kernel(
    const float* __restrict__ chan, const float* __restrict__ pooled,
    const float* __restrict__ embed, const int* __restrict__ sos,
    const float* __restrict__ Wq, const float* __restrict__ bq,
    const float* __restrict__ Wk, const float* __restrict__ bk,
    const float* __restrict__ Wv, const float* __restrict__ bv,
    const float* __restrict__ Wih, const float* __restrict__ Whh,
    const float* __restrict__ bih, const float* __restrict__ bhh,
    const float* __restrict__ projW, const float* __restrict__ projb,
    const float* __restrict__ hattW, const float* __restrict__ hattb,
    float* __restrict__ ws, float* __restrict__ out, int staged) {
  __shared__ __align__(16) float smem[8704];
  int blk = blockIdx.x, tid = threadIdx.x;
  unsigned bar_target = 0;

  float* keysT   = ws;
  float* valuesT = keysT + B * S * 512;
  float* emb     = valuesT + B * S * 512;
  float* h       = emb + B * H;
  float* c       = h + L * B * H;
  float* hmid    = c + L * B * H;
  float* cat     = hmid + L * B * H;
  float* q       = cat + L * B * 1024;
  float* logits  = q + L * B * H;
  unsigned* bar  = (unsigned*)(logits + B * V);
  float* slog    = logits + B * V + 64;

  // ---- S0: kv precompute (blocks 0..255) + state init (256..383) ----
  if (blk < 256) {
    float* ch = smem;             // 64*52
    float* wk = smem + 3328;      // 49*52
    float* wv = smem + 5876;      // 49*52
    int b = blk >> 3, dt = blk & 7;
    for (int i = tid; i < 49 * 49; i += 256) {
      int s = i / 49, j = i % 49;
      wk[s * 52 + j] = Wk[i]; wv[s * 52 + j] = Wv[i];
    }
    for (int i = tid; i < 64 * 49; i += 256) {
      int d = i / 49, j = i % 49;
      ch[d * 52 + j] = chan[((size_t)b * 512 + dt * 64 + d) * S + j];
    }
    __syncthreads();
    int dl = tid >> 2, sq = tid & 3;
    for (int s = sq; s < S; s += 4) {
      float ak = bk[s], av = bv[s];
      for (int j = 0; j < 49; ++j) {
        float cv = ch[dl * 52 + j];
        ak += cv * wk[s * 52 + j];
        av += cv * wv[s * 52 + j];
      }
      int d = dt * 64 + dl;
      keysT[((size_t)b * S + s) * H + d] = tanhf(ak);
      valuesT[((size_t)b * S + s) * H + d] = tanhf(av);
    }
  } else if (blk < 384) {
    int idx = (blk - 256) * 256 + tid;
    float p = pooled[idx & (B * H - 1)];
    h[idx] = p;
    c[idx] = p;
    if (idx < B * H) emb[idx] = embed[sos[0] * H + (idx & (H - 1))];
  }
  grid_bar(bar, bar_target, tid);

  // ---- S1: initial projection (output column 0 from emb) ----
  {
    float* oc = staged ? slog : out;
    for (int tt = blk; tt < 625; tt += 512)
      dev_proj_tile(emb, projW, projb, logits, oc, staged ? 0 : 1, 0,
                    tt * 16, smem, tid);
  }
  grid_bar(bar, bar_target, tid);

  // ---- main decode loop ----
  for (int t = 0; t < T - 1; ++t) {
    dev_lstm_layer(emb, h, c, Wih, Whh, bih, bhh, hmid, blk, smem, tid);
    grid_bar(bar, bar_target, tid);
    dev_lstm_layer(hmid, h + B * H, c + B * H,
                   Wih + 4 * H * H, Whh + 4 * H * H,
                   bih + 4 * H, bhh + 4 * H, hmid + B * H, blk, smem, tid);
    grid_bar(bar, bar_target, tid);
    {
      float* oc = staged ? (slog + (size_t)(t + 1) * B * V) : out;
      for (int tt = blk; tt < 689; tt += 512) {
        if (tt < 625)
          dev_proj_tile(hmid + B * H, projW, projb, logits, oc,
                        staged ? 0 : 1, t + 1, tt * 16, smem, tid);
        else
          dev_q_tile(hmid, Wq, bq, q, tt - 625, smem, tid);
      }
    }
    grid_bar(bar, bar_target, tid);
    if (blk < 64) dev_sattn(q, keysT, valuesT, hmid, cat, blk, smem, tid);
    else if (blk < 96) dev_argmax_embed(logits, embed, emb, blk - 64, smem, tid);
    grid_bar(bar, bar_target, tid);
    if (blk < 128) dev_hatt(cat, hattW, hattb, h, blk, smem, tid);
    grid_bar(bar, bar_target, tid);
  }

  // ---- finalize: transpose slog[t][b][v] -> out[b][v][t] ----
  if (staged) {
    for (int u = blk; u < 1250; u += 512) {
      int idx = u * 256 + tid;
      float vals[T];
#pragma unroll
      for (int t = 0; t < T; ++t) vals[t] = slog[(size_t)t * (B * V) + idx];
#pragma unroll
      for (int t = 0; t < T; t += 4)
        *(float4*)&out[(size_t)idx * T + t] =
            make_float4(vals[t], vals[t + 1], vals[t + 2], vals[t + 3]);
    }
  }
}

}  // namespace

extern "C" void kernel_launch(void* const* d_in, const int* in_sizes, int n_in,
                              void* d_out, int out_size, void* d_ws, size_t ws_size,
                              hipStream_t stream) {
  const float* chan   = (const float*)d_in[0];
  const float* pooled = (const float*)d_in[1];
  const float* embed  = (const float*)d_in[2];
  const float* Wq     = (const float*)d_in[3];
  const float* bq     = (const float*)d_in[4];
  const float* Wk     = (const float*)d_in[5];
  const float* bk     = (const float*)d_in[6];
  const float* Wv     = (const float*)d_in[7];
  const float* bv     = (const float*)d_in[8];
  const float* Wih    = (const float*)d_in[9];
  const float* Whh    = (const float*)d_in[10];
  const float* bih    = (const float*)d_in[11];
  const float* bhh    = (const float*)d_in[12];
  const float* projW  = (const float*)d_in[13];
  const float* projb  = (const float*)d_in[14];
  const float* hattW  = (const float*)d_in[15];
  const float* hattb  = (const float*)d_in[16];
  const int*   sos    = (const int*)d_in[17];

  float* out = (float*)d_out;
  float* ws  = (float*)d_ws;

  // workspace layout (floats): keysT, valuesT, emb, h, c, hmid, cat, q,
  // logits, [bar: 64 floats], slog
  size_t base_floats = (size_t)(B * S * 512) * 2 + B * H + 3 * (L * B * H) +
                       L * B * 1024 + L * B * H + B * V + 64;
  int staged = ws_size >= (base_floats + (size_t)T * B * V) * sizeof(float) ? 1 : 0;

  unsigned* bar = (unsigned*)(ws + base_floats - 64 - (size_t)T * B * V * 0) ;
  // recompute precisely (mirror of device layout):
  {
    float* p = ws;
    p += B * S * 512;        // keysT
    p += B * S * 512;        // valuesT
    p += B * H;              // emb
    p += L * B * H;          // h
    p += L * B * H;          // c
    p += L * B * H;          // hmid
    p += L * B * 1024;       // cat
    p += L * B * H;          // q
    p += B * V;              // logits
    bar = (unsigned*)p;
  }

  bar_init_kernel<<<1, 64, 0, stream>>>(bar);
  persist_kernel<<<NBLK, 256, 0, stream>>>(
      chan, pooled, embed, sos, Wq, bq, Wk, bk, Wv, bv,
      Wih, Whh, bih, bhh, projW, projb, hattW, hattb, ws, out, staged);
}

// Round 6
// 2397.662 us; speedup vs baseline: 4.2473x; 4.2473x over previous
//
#include <hip/hip_runtime.h>

namespace {

constexpr int B = 32, H = 512, L = 2, T = 20, V = 10000, S = 49;

__device__ __forceinline__ float sigf(float x) { return 1.0f / (1.0f + expf(-x)); }
__device__ __forceinline__ float dot4(float4 a, float4 b) {
  return a.x*b.x + a.y*b.y + a.z*b.z + a.w*b.w;
}

// ---------------- keys/values precompute (once), transposed layout ---------
__global__ __launch_bounds__(256) void kv_kernel(
    const float* __restrict__ chan,
    const float* __restrict__ Wk, const float* __restrict__ bk,
    const float* __restrict__ Wv, const float* __restrict__ bv,
    float* __restrict__ keysT, float* __restrict__ valuesT) {
  __shared__ float ch[64][52];
  __shared__ float wk[49][52], wv[49][52];
  int b = blockIdx.x >> 3, dt = blockIdx.x & 7;
  int tid = threadIdx.x;
  for (int i = tid; i < 49 * 49; i += 256) {
    int s = i / 49, j = i % 49;
    wk[s][j] = Wk[i]; wv[s][j] = Wv[i];
  }
  for (int i = tid; i < 64 * 49; i += 256) {
    int d = i / 49, j = i % 49;
    ch[d][j] = chan[((size_t)b * 512 + dt * 64 + d) * S + j];
  }
  __syncthreads();
  int dl = tid >> 2, sq = tid & 3;
  for (int s = sq; s < S; s += 4) {
    float ak = bk[s], av = bv[s];
    for (int j = 0; j < 49; ++j) {
      float cv = ch[dl][j];
      ak += cv * wk[s][j];
      av += cv * wv[s][j];
    }
    int d = dt * 64 + dl;
    keysT[((size_t)b * S + s) * H + d] = tanhf(ak);
    valuesT[((size_t)b * S + s) * H + d] = tanhf(av);
  }
}

// ---------------- state init ----------------
__global__ void init_kernel(const float* __restrict__ pooled,
                            const float* __restrict__ embed,
                            const int* __restrict__ sos,
                            float* __restrict__ emb, float* __restrict__ h,
                            float* __restrict__ c) {
  int idx = blockIdx.x * 256 + threadIdx.x;   // L*B*H = 32768
  float p = pooled[idx & (B * H - 1)];
  h[idx] = p;
  c[idx] = p;
  if (idx < B * H) emb[idx] = embed[sos[0] * H + (idx & (H - 1))];
}

// ---------------- LSTM cell: block = one hi; weights in registers ---------
// grid 512 (hi). thread = ko(16 K-slice) x rr(4 gate) x bh(4 waves of 8 b).
// No activation staging: x/h rows are L1/L2-hot (64 KB each, read by all blocks).
__global__ __launch_bounds__(256) void lstm_kernel(
    const float* __restrict__ x, const float* __restrict__ hprev,
    const float* __restrict__ cprev,
    const float* __restrict__ Wih, const float* __restrict__ Whh,
    const float* __restrict__ bih, const float* __restrict__ bhh,
    float* __restrict__ hout, float* __restrict__ cout) {
  __shared__ float gbuf[128];
  int tid = threadIdx.x;
  int hi = blockIdx.x;
  int ko = tid & 15, rr = (tid >> 4) & 3, bh = tid >> 6;
  const float* wihr = Wih + ((size_t)rr * H + hi) * H + ko * 4;
  const float* whhr = Whh + ((size_t)rr * H + hi) * H + ko * 4;
  float4 wi[8], wh[8];
#pragma unroll
  for (int kk = 0; kk < 8; ++kk) {
    wi[kk] = *(const float4*)&wihr[kk * 64];
    wh[kk] = *(const float4*)&whhr[kk * 64];
  }
  float acc[8];
#pragma unroll
  for (int j = 0; j < 8; ++j) {
    int b = bh * 8 + j;
    const float* xb = x + (size_t)b * H + ko * 4;
    const float* hb = hprev + (size_t)b * H + ko * 4;
    float a = 0.f;
#pragma unroll
    for (int kk = 0; kk < 8; ++kk) {
      a += dot4(*(const float4*)&xb[kk * 64], wi[kk]);
      a += dot4(*(const float4*)&hb[kk * 64], wh[kk]);
    }
    acc[j] = a;
  }
#pragma unroll
  for (int j = 0; j < 8; ++j) {
    acc[j] += __shfl_xor(acc[j], 1);
    acc[j] += __shfl_xor(acc[j], 2);
    acc[j] += __shfl_xor(acc[j], 4);
    acc[j] += __shfl_xor(acc[j], 8);
  }
  if (ko == 0) {
    float bias = bih[rr * H + hi] + bhh[rr * H + hi];
#pragma unroll
    for (int j = 0; j < 8; ++j) gbuf[rr * 32 + bh * 8 + j] = acc[j] + bias;
  }
  __syncthreads();
  if (tid < 32) {
    int b = tid;
    float gi = gbuf[b], gf = gbuf[32 + b], gg = gbuf[64 + b], go = gbuf[96 + b];
    float c2 = sigf(gf) * cprev[b * H + hi] + sigf(gi) * tanhf(gg);
    hout[b * H + hi] = sigf(go) * tanhf(c2);
    cout[b * H + hi] = c2;
  }
}

// ---------------- fused vocab projection + q GEMV (no LDS) ----------------
// blocks 0..624: proj, 16 v-rows x 32 b. blocks 625..688: q tiles (16 j x 32 lb).
__global__ __launch_bounds__(256) void projq_kernel(
    const float* __restrict__ xin,
    const float* __restrict__ projW, const float* __restrict__ projb,
    float* __restrict__ logits, float* __restrict__ ocol, int direct, int tcol,
    const float* __restrict__ hmid_all, const float* __restrict__ Wq,
    const float* __restrict__ bq, float* __restrict__ q) {
  int blk = blockIdx.x, tid = threadIdx.x;
  int ko = tid & 15, vl = tid >> 4;
  if (blk < 625) {
    int v = blk * 16 + vl;
    const float* wrow = projW + (size_t)v * H + ko * 4;
    float4 w[8];
#pragma unroll
    for (int kk = 0; kk < 8; ++kk) w[kk] = *(const float4*)&wrow[kk * 64];
    float acc[32];
    for (int b = 0; b < 32; ++b) {
      const float* xb = xin + (size_t)b * H + ko * 4;
      float a = 0.f;
#pragma unroll
      for (int kk = 0; kk < 8; ++kk)
        a += dot4(*(const float4*)&xb[kk * 64], w[kk]);
      acc[b] = a;
    }
#pragma unroll
    for (int b = 0; b < 32; ++b) {
      acc[b] += __shfl_xor(acc[b], 1);
      acc[b] += __shfl_xor(acc[b], 2);
      acc[b] += __shfl_xor(acc[b], 4);
      acc[b] += __shfl_xor(acc[b], 8);
    }
    if (ko == 0) {
      float bias = projb[v];
      for (int b = 0; b < 32; ++b) {
        float r = acc[b] + bias;
        logits[b * V + v] = r;
        if (direct) ocol[((size_t)b * V + v) * T + tcol] = r;
        else        ocol[b * V + v] = r;
      }
    }
  } else {
    int b2 = blk - 625;
    int lg = b2 & 1, jg = b2 >> 1;
    int j = jg * 16 + vl;
    const float* wrow = Wq + (size_t)j * H + ko * 4;
    float4 w[8];
#pragma unroll
    for (int kk = 0; kk < 8; ++kk) w[kk] = *(const float4*)&wrow[kk * 64];
    float acc[32];
    for (int b = 0; b < 32; ++b) {
      const float* xb = hmid_all + ((size_t)lg * 32 + b) * H + ko * 4;
      float a = 0.f;
#pragma unroll
      for (int kk = 0; kk < 8; ++kk)
        a += dot4(*(const float4*)&xb[kk * 64], w[kk]);
      acc[b] = a;
    }
#pragma unroll
    for (int b = 0; b < 32; ++b) {
      acc[b] += __shfl_xor(acc[b], 1);
      acc[b] += __shfl_xor(acc[b], 2);
      acc[b] += __shfl_xor(acc[b], 4);
      acc[b] += __shfl_xor(acc[b], 8);
    }
    if (ko == 0) {
      float bias = bq[j];
      for (int b = 0; b < 32; ++b)
        q[((size_t)lg * 32 + b) * H + j] = tanhf(acc[b] + bias);
    }
  }
}

// ---------------- scores/softmax/attn/cat (blk<64) + argmax (64..95) ------
__global__ __launch_bounds__(256) void sattnarg_kernel(
    const float* __restrict__ q, const float* __restrict__ keysT,
    const float* __restrict__ valuesT, const float* __restrict__ hmid,
    float* __restrict__ cat,
    const float* __restrict__ logits, const float* __restrict__ embed,
    float* __restrict__ emb) {
  __shared__ __align__(16) float smem[656];
  int blk = blockIdx.x, tid = threadIdx.x;
  if (blk < 64) {
    float* qv = smem;          // 528 (4 chunks of 132)
    float* scl = smem + 528;   // 64
    float* wts = smem + 592;   // 64
    int lb = blk;
    int b = lb & 31;
    {
      int c0 = tid, c1 = tid + 256;
      qv[(c0 >> 7) * 132 + (c0 & 127)] = q[lb * H + c0];
      qv[(c1 >> 7) * 132 + (c1 & 127)] = q[lb * H + c1];
    }
    __syncthreads();
    int kq = tid & 3, sl = tid >> 2;
    float acc = 0.f;
    if (sl < S) {
      const float* kr = keysT + ((size_t)b * S + sl) * H + kq * 128;
      const float* qr = &qv[kq * 132];
      for (int k = 0; k < 128; k += 4)
        acc += dot4(*(const float4*)&qr[k], *(const float4*)&kr[k]);
    }
    acc += __shfl_xor(acc, 1);
    acc += __shfl_xor(acc, 2);
    if (kq == 0 && sl < S) scl[sl] = acc * (1.0f / 7.0f);
    __syncthreads();
    if (tid < 64) {
      float sc = (tid < S) ? scl[tid] : -3.4e38f;
      float m = sc;
      for (int o = 32; o > 0; o >>= 1) m = fmaxf(m, __shfl_xor(m, o));
      float e = (tid < S) ? expf(sc - m) : 0.f;
      float sum = e;
      for (int o = 32; o > 0; o >>= 1) sum += __shfl_xor(sum, o);
      if (tid < S) wts[tid] = e / sum;
    }
    __syncthreads();
    float acc0 = 0.f, acc1 = 0.f;
    for (int s = 0; s < S; ++s) {
      float w = wts[s];
      const float* vr = valuesT + ((size_t)b * S + s) * H;
      acc0 += w * vr[tid];
      acc1 += w * vr[tid + 256];
    }
    cat[lb * 1024 + tid] = acc0;
    cat[lb * 1024 + tid + 256] = acc1;
    cat[lb * 1024 + 512 + tid] = hmid[lb * H + tid];
    cat[lb * 1024 + 768 + tid] = hmid[lb * H + tid + 256];
  } else {
    int b = blk - 64;
    float* sv = smem;
    int* si = (int*)(smem + 256);
    float best = -3.4e38f;
    int bi = 0x7fffffff;
    for (int it = 0; it < 10; ++it) {
      int v0 = it * 1024 + tid * 4;
      if (v0 < V) {   // V%4==0 -> whole float4 valid
        float4 lv = *(const float4*)&logits[b * V + v0];
        if (lv.x > best) { best = lv.x; bi = v0; }
        if (lv.y > best) { best = lv.y; bi = v0 + 1; }
        if (lv.z > best) { best = lv.z; bi = v0 + 2; }
        if (lv.w > best) { best = lv.w; bi = v0 + 3; }
      }
    }
    sv[tid] = best; si[tid] = bi;
    __syncthreads();
    for (int st = 128; st > 0; st >>= 1) {
      if (tid < st) {
        float ov = sv[tid + st]; int oi = si[tid + st];
        if (ov > sv[tid] || (ov == sv[tid] && oi < si[tid])) { sv[tid] = ov; si[tid] = oi; }
      }
      __syncthreads();
    }
    int idx = si[0];
    for (int i = tid; i < H; i += 256) emb[b * H + i] = embed[(size_t)idx * H + i];
  }
}

// ---------------- gated hidden update (no LDS): grid 256 ----------------
// blk = lbg(8 groups of 8 lb) + jg(32 groups of 16 j)*8
__global__ __launch_bounds__(256) void hatt_kernel(
    const float* __restrict__ cat, const float* __restrict__ hattW,
    const float* __restrict__ hattb, float* __restrict__ h) {
  int blk = blockIdx.x, tid = threadIdx.x;
  int lbg = blk & 7, jg = blk >> 3;
  int ko = tid & 15, jl = tid >> 4;
  int j = jg * 16 + jl;
  const float* wrow = hattW + (size_t)j * 1024 + ko * 4;
  float4 w[16];
#pragma unroll
  for (int kk = 0; kk < 16; ++kk) w[kk] = *(const float4*)&wrow[kk * 64];
  float acc[8];
#pragma unroll
  for (int lb = 0; lb < 8; ++lb) {
    const float* cb = cat + ((size_t)lbg * 8 + lb) * 1024 + ko * 4;
    float a = 0.f;
#pragma unroll
    for (int kk = 0; kk < 16; ++kk)
      a += dot4(*(const float4*)&cb[kk * 64], w[kk]);
    acc[lb] = a;
  }
#pragma unroll
  for (int lb = 0; lb < 8; ++lb) {
    acc[lb] += __shfl_xor(acc[lb], 1);
    acc[lb] += __shfl_xor(acc[lb], 2);
    acc[lb] += __shfl_xor(acc[lb], 4);
    acc[lb] += __shfl_xor(acc[lb], 8);
  }
  if (ko == 0) {
    float bias = hattb[j];
    for (int lb = 0; lb < 8; ++lb)
      h[((size_t)lbg * 8 + lb) * H + j] = tanhf(acc[lb] + bias);
  }
}

// ---------------- final transpose (staged): slog[t][b][v] -> out[b][v][t] --
__global__ __launch_bounds__(256) void finalize_kernel(
    const float* __restrict__ slog, float* __restrict__ outp) {
  int idx = blockIdx.x * 256 + threadIdx.x;   // b*V + v, exact 320000
  float vals[T];
#pragma unroll
  for (int t = 0; t < T; ++t) vals[t] = slog[(size_t)t * (B * V) + idx];
#pragma unroll
  for (int t = 0; t < T; t += 4)
    *(float4*)&outp[(size_t)idx * T + t] =
        make_float4(vals[t], vals[t + 1], vals[t + 2], vals[t + 3]);
}

}  // namespace

extern "C" void kernel_launch(void* const* d_in, const int* in_sizes, int n_in,
                              void* d_out, int out_size, void* d_ws, size_t ws_size,
                              hipStream_t stream) {
  const float* chan   = (const float*)d_in[0];
  const float* pooled = (const float*)d_in[1];
  const float* embed  = (const float*)d_in[2];
  const float* Wq     = (const float*)d_in[3];
  const float* bq     = (const float*)d_in[4];
  const float* Wk     = (const float*)d_in[5];
  const float* bk     = (const float*)d_in[6];
  const float* Wv     = (const float*)d_in[7];
  const float* bv     = (const float*)d_in[8];
  const float* Wih    = (const float*)d_in[9];
  const float* Whh    = (const float*)d_in[10];
  const float* bih    = (const float*)d_in[11];
  const float* bhh    = (const float*)d_in[12];
  const float* projW  = (const float*)d_in[13];
  const float* projb  = (const float*)d_in[14];
  const float* hattW  = (const float*)d_in[15];
  const float* hattb  = (const float*)d_in[16];
  const int*   sos    = (const int*)d_in[17];

  float* out = (float*)d_out;
  float* ws  = (float*)d_ws;

  float* keysT   = ws;
  float* valuesT = keysT + B * S * 512;
  float* emb     = valuesT + B * S * 512;
  float* h       = emb + B * H;
  float* c       = h + L * B * H;
  float* hmid    = c + L * B * H;
  float* cat     = hmid + L * B * H;
  float* q       = cat + L * B * 1024;
  float* logits  = q + L * B * H;
  float* slog    = logits + B * V;

  size_t base_floats = (size_t)(slog - ws);
  int staged = ws_size >= (base_floats + (size_t)T * B * V) * sizeof(float) ? 1 : 0;

  kv_kernel<<<256, 256, 0, stream>>>(chan, Wk, bk, Wv, bv, keysT, valuesT);
  init_kernel<<<(L * B * H) / 256, 256, 0, stream>>>(pooled, embed, sos, emb, h, c);
  {
    float* oc = staged ? slog : out;
    projq_kernel<<<625, 256, 0, stream>>>(emb, projW, projb, logits, oc,
                                          staged ? 0 : 1, 0, hmid, Wq, bq, q);
  }

  for (int t = 0; t < T - 1; ++t) {
    float* oc = staged ? (slog + (size_t)(t + 1) * B * V) : out;
    lstm_kernel<<<512, 256, 0, stream>>>(emb, h, c, Wih, Whh, bih, bhh, hmid, c);
    lstm_kernel<<<512, 256, 0, stream>>>(hmid, h + B * H, c + B * H,
                                         Wih + 4 * H * H, Whh + 4 * H * H,
                                         bih + 4 * H, bhh + 4 * H,
                                         hmid + B * H, c + B * H);
    projq_kernel<<<689, 256, 0, stream>>>(hmid + B * H, projW, projb, logits, oc,
                                          staged ? 0 : 1, t + 1, hmid, Wq, bq, q);
    sattnarg_kernel<<<96, 256, 0, stream>>>(q, keysT, valuesT, hmid, cat,
                                            logits, embed, emb);
    hatt_kernel<<<256, 256, 0, stream>>>(cat, hattW, hattb, h);
  }

  if (staged) finalize_kernel<<<(B * V) / 256, 256, 0, stream>>>(slog, out);
}